// Round 7
// baseline (315.873 us; speedup 1.0000x reference)
//
#include <hip/hip_runtime.h>
#include <cstddef>
#include <cstdint>

#define D_MODEL 1024
#define D_STATE 16
#define D_CONV 4
#define D_INNER 2048
#define IN_DIM 256
#define OUT_DIM 256
#define BATCH 2
#define SEQ 1024
#define NTOK (BATCH*SEQ)
#define PROJ_N (2*D_STATE + D_INNER) // 2080
#define CHUNK 64
#define NCHUNK (SEQ/CHUNK)           // 16

typedef __attribute__((ext_vector_type(8))) short bf16x8;
typedef __attribute__((ext_vector_type(16))) float f32x16;

__device__ __forceinline__ float siluf(float x){ return x / (1.f + __expf(-x)); }

__device__ __forceinline__ unsigned short f2bf(float f) {
  uint32_t x = __float_as_uint(f);
  uint32_t r = x + 0x7fffu + ((x >> 16) & 1u);
  return (unsigned short)(r >> 16);
}
__device__ __forceinline__ float bf2f(unsigned short u) {
  return __uint_as_float(((uint32_t)u) << 16);
}

__device__ __forceinline__ void gload16(const void* g, void* l) {
  __builtin_amdgcn_global_load_lds((const __attribute__((address_space(1))) void*)g,
                                   (__attribute__((address_space(3))) void*)l, 16, 0, 0);
}

template<int N> __device__ __forceinline__ void waitvm() {
  if constexpr (N == 0) asm volatile("s_waitcnt vmcnt(0)" ::: "memory");
  else if constexpr (N == 2) asm volatile("s_waitcnt vmcnt(2)" ::: "memory");
  else if constexpr (N == 3) asm volatile("s_waitcnt vmcnt(3)" ::: "memory");
  else if constexpr (N == 4) asm volatile("s_waitcnt vmcnt(4)" ::: "memory");
  else if constexpr (N == 6) asm volatile("s_waitcnt vmcnt(6)" ::: "memory");
  else                       asm volatile("s_waitcnt vmcnt(8)" ::: "memory");
}

// ------------- fused weight prep: 6 transposes + x cast + WxT pad zero -------
__device__ __forceinline__ void tc_tile(float (*tile)[33], const float* __restrict__ in,
                                        unsigned short* __restrict__ out,
                                        int R, int C, int tcx, int tcy, int tid)
{
  const int bc = tcx * 32, br = tcy * 32;
  const int tx = tid & 31, ty = tid >> 5;
  #pragma unroll
  for (int i = 0; i < 4; ++i) {
    int r = ty + i*8;
    tile[r][tx] = in[(size_t)(br + r)*C + bc + tx];
  }
  __syncthreads();
  const int otx = tid & 7, oty = tid >> 3;
  ushort4 v;
  v.x = f2bf(tile[otx*4+0][oty]);
  v.y = f2bf(tile[otx*4+1][oty]);
  v.z = f2bf(tile[otx*4+2][oty]);
  v.w = f2bf(tile[otx*4+3][oty]);
  *(ushort4*)&out[(size_t)(bc + oty)*R + br + otx*4] = v;
}

__global__ __launch_bounds__(256)
void prep_k(const float* __restrict__ x, const float* __restrict__ Wiw,
            const float* __restrict__ Win, const float* __restrict__ Wx,
            const float* __restrict__ Wdt, const float* __restrict__ Wout,
            const float* __restrict__ Wwr,
            unsigned short* __restrict__ xb16, unsigned short* __restrict__ WiwT,
            unsigned short* __restrict__ WinT, unsigned short* __restrict__ WxT,
            unsigned short* __restrict__ WdtT, unsigned short* __restrict__ WoutT,
            unsigned short* __restrict__ WwrT)
{
  __shared__ float tile[32][33];
  const int tid = threadIdx.x;
  int id = blockIdx.x;
  if (id < 4096)  { tc_tile(tile, Win,  WinT,  1024, 4096, id % 128, id / 128, tid); return; }
  id -= 4096;
  if (id < 4160)  { tc_tile(tile, Wx,   WxT,   2048, 2080, id % 65,  id / 65,  tid); return; }
  id -= 4160;
  if (id < 4096)  { tc_tile(tile, Wdt,  WdtT,  2048, 2048, id % 64,  id / 64,  tid); return; }
  id -= 4096;
  if (id < 2048)  { tc_tile(tile, Wout, WoutT, 2048, 1024, id % 32,  id / 32,  tid); return; }
  id -= 2048;
  if (id < 256)   { tc_tile(tile, Wwr,  WwrT,  1024, 256,  id % 8,   id / 8,   tid); return; }
  id -= 256;
  if (id < 256)   { tc_tile(tile, Wiw,  WiwT,  256,  1024, id % 32,  id / 32,  tid); return; }
  id -= 256;
  if (id < 512) {                                  // cast x -> bf16 (float4)
    int i = id * 256 + tid;                        // < 131072 = NTOK*IN_DIM/4
    float4 v = ((const float4*)x)[i];
    ushort4 o;
    o.x = f2bf(v.x); o.y = f2bf(v.y); o.z = f2bf(v.z); o.w = f2bf(v.w);
    ((ushort4*)xb16)[i] = o;
    return;
  }
  id -= 512;
  {                                                // zero WxT pad rows 2080..2175
    unsigned short* p = WxT + (size_t)(2080 + id) * 2048 + tid * 8;
    ushort4 z = {0,0,0,0};
    *(ushort4*)p = z; *(ushort4*)(p + 4) = z;
  }
}

// ---------------- bf16 MFMA GEMM: BMxBN tile, 4 waves, 32x32x16 frags --------
// B pre-transposed: B[N][K] row-major. 4-buffer LDS (depth-3 prefetch), raw
// s_barrier, counted vmcnt, strength-reduced addressing, XCD-chunked swizzle.
// Requires (K/32) % 4 == 0, M == 2048 (gridDim.y == 32 for BM=64), nwg % 8 == 0.
// MODE: 0 f32 out (+bias); 1 softplus(v+bias) f32; 2 bf16 out;
//       3 split xz -> out0=xb fp32 [M][2048] (c<2048), out1=zb bf16 [M][2048];
//       4 proj -> out0=BC fp32 [M][32] (c<32), out1=g bf16 [M][2048]
template<int BM, int BN, int MODE>
__global__ __launch_bounds__(256)
void gemm_bf16(const unsigned short* __restrict__ A, const unsigned short* __restrict__ B,
               int M, int N, int K, int lda, int ldb,
               const float* __restrict__ bias,
               void* __restrict__ out0, void* __restrict__ out1)
{
  constexpr int FM = BM / 64;           // 32x32 frags per wave, M dir
  constexpr int FN = BN / 64;
  constexpr int ROWS = BM + BN;
  constexpr int G = ROWS / 16;          // 16-row staging groups
  constexpr int IPW = G / 4;            // gload16 issues per wave per stage
  __shared__ __align__(1024) unsigned short S[4][ROWS*32];

  const int tid = threadIdx.x;
  const int lane = tid & 63, w = tid >> 6;

  // XCD-chunked bijective swizzle; column-major within XCD (B-panel stays L2-hot)
  const int nwg = (int)(gridDim.x * gridDim.y);
  int lin = (int)(blockIdx.y * gridDim.x + blockIdx.x);
  lin = (lin & 7) * (nwg >> 3) + (lin >> 3);
  const int by = lin & 31, bx = lin >> 5;          // gridDim.y == 32 always
  const int row0 = by * BM, col0 = bx * BN;

  const int wr = (w >> 1) * (BM/2), wc = (w & 1) * (BN/2);
  const int lrq = lane >> 2;     // row within 16-row staging group
  const int lg  = lane & 3;      // dest granule slot
  const int l31 = lane & 31, lh = lane >> 5;

  // K-invariant fragment LDS offsets; swizzle f(r) = (r>>1)&3
  int afo[FM][2], bfo[FN][2];
  #pragma unroll
  for (int fi = 0; fi < FM; ++fi)
    #pragma unroll
    for (int h = 0; h < 2; ++h) {
      const int r = wr + fi*32 + l31;
      const int slot = (2*h + lh) ^ ((r >> 1) & 3);
      afo[fi][h] = (r>>4)*512 + (r&15)*32 + slot*8;
    }
  #pragma unroll
  for (int fj = 0; fj < FN; ++fj)
    #pragma unroll
    for (int h = 0; h < 2; ++h) {
      const int r = wc + fj*32 + l31;
      const int slot = (2*h + lh) ^ ((r >> 1) & 3);
      bfo[fj][h] = BM*32 + (r>>4)*512 + (r&15)*32 + slot*8;
    }

  // staging: incremented global pointers + fixed LDS dests
  const unsigned short* src[IPW];
  int ldso[IPW];
  #pragma unroll
  for (int i = 0; i < IPW; ++i) {
    const int base = (w + i*4) * 16;             // wave-uniform group base row
    const int lr = base + lrq;
    const int gs = lg ^ ((lr >> 1) & 3);         // matching involution
    ldso[i] = base * 32;
    src[i] = (base < BM) ? A + (size_t)(row0 + lr) * lda + gs*8
                         : B + (size_t)(col0 + lr - BM) * ldb + gs*8;
  }

  f32x16 acc[FM][FN];
  #pragma unroll
  for (int i=0;i<FM;i++)
    #pragma unroll
    for (int j=0;j<FN;j++)
      #pragma unroll
      for (int q=0;q<16;q++) acc[i][j][q] = 0.f;

  const int NT = K >> 5;

  auto stage = [&](int buf) {
    #pragma unroll
    for (int i = 0; i < IPW; ++i) {
      gload16(src[i], &S[buf][ldso[i]]);
      src[i] += 32;                              // next K-tile
    }
  };

  stage(0); stage(1); stage(2);

  for (int kt = 0; kt < NT; kt += 4) {
    #pragma unroll
    for (int j = 0; j < 4; ++j) {                // buffer index == j (NT%4==0)
      const int rem = NT - (kt + j);
      if (rem == 1)      waitvm<0>();
      else if (rem == 2) waitvm<IPW>();
      else               waitvm<2*IPW>();
      __builtin_amdgcn_s_barrier();
      if (kt + j + 3 < NT) stage((j + 3) & 3);

      const unsigned short* Sb = &S[j][0];
      bf16x8 af[FM][2], bfv[FN][2];
      #pragma unroll
      for (int fi = 0; fi < FM; ++fi) {
        af[fi][0] = *(const bf16x8*)(Sb + afo[fi][0]);
        af[fi][1] = *(const bf16x8*)(Sb + afo[fi][1]);
      }
      #pragma unroll
      for (int fj = 0; fj < FN; ++fj) {
        bfv[fj][0] = *(const bf16x8*)(Sb + bfo[fj][0]);
        bfv[fj][1] = *(const bf16x8*)(Sb + bfo[fj][1]);
      }
      #pragma unroll
      for (int h = 0; h < 2; ++h)
        #pragma unroll
        for (int fi = 0; fi < FM; ++fi)
          #pragma unroll
          for (int fj = 0; fj < FN; ++fj)
            acc[fi][fj] = __builtin_amdgcn_mfma_f32_32x32x16_bf16(af[fi][h], bfv[fj][h], acc[fi][fj], 0, 0, 0);
      __builtin_amdgcn_sched_barrier(0);   // pin lgkm waits before next barrier
      asm volatile("" ::: "memory");
    }
  }

  // epilogue: C/D layout col=lane&31, row=(reg&3)+8*(reg>>2)+4*(lane>>5)
  #pragma unroll
  for (int fi=0; fi<FM; fi++){
    #pragma unroll
    for (int fj=0; fj<FN; fj++){
      const int c = col0 + wc + fj*32 + l31;
      #pragma unroll
      for (int reg=0; reg<16; reg++){
        const int r = row0 + wr + fi*32 + 4*lh + (reg&3) + 8*(reg>>2);
        float v = acc[fi][fj][reg];
        if constexpr (MODE == 0) {
          if (c < N) ((float*)out0)[(size_t)r*N + c] = bias ? v + bias[c] : v;
        } else if constexpr (MODE == 1) {
          if (c < N) { v += bias[c]; v = (v > 20.f) ? v : log1pf(__expf(v));
                       ((float*)out0)[(size_t)r*N + c] = v; }
        } else if constexpr (MODE == 2) {
          if (c < N) ((unsigned short*)out0)[(size_t)r*N + c] = f2bf(v);
        } else if constexpr (MODE == 3) {
          if (c < 2048) ((float*)out0)[(size_t)r*2048 + c] = v;
          else          ((unsigned short*)out1)[(size_t)r*2048 + (c - 2048)] = f2bf(v);
        } else {
          if (c < 32) ((float*)out0)[(size_t)r*32 + c] = v;
          else if (c < N) ((unsigned short*)out1)[(size_t)r*2048 + (c - 32)] = f2bf(v);
        }
      }
    }
  }
}

// LayerNorm: read fp32 h, write bf16
__global__ __launch_bounds__(256)
void ln_k(const float* __restrict__ h, const float* __restrict__ gamma,
          const float* __restrict__ beta, unsigned short* __restrict__ hb)
{
  const int row = blockIdx.x;
  const float* p = h + (size_t)row * D_MODEL;
  float s = 0.f, s2 = 0.f;
  for (int i = threadIdx.x; i < D_MODEL; i += 256) { float v = p[i]; s += v; s2 += v*v; }
  #pragma unroll
  for (int off = 32; off; off >>= 1) { s += __shfl_down(s, off, 64); s2 += __shfl_down(s2, off, 64); }
  __shared__ float ss[4], ss2[4];
  __shared__ float smu, sinv;
  const int wid = threadIdx.x >> 6;
  if ((threadIdx.x & 63) == 0) { ss[wid] = s; ss2[wid] = s2; }
  __syncthreads();
  if (threadIdx.x == 0) {
    float S = ss[0]+ss[1]+ss[2]+ss[3];
    float S2 = ss2[0]+ss2[1]+ss2[2]+ss2[3];
    float mu = S * (1.f / D_MODEL);
    float var = S2 * (1.f / D_MODEL) - mu * mu;
    smu = mu; sinv = rsqrtf(var + 1e-5f);
  }
  __syncthreads();
  const float mu = smu, inv = sinv;
  unsigned short* q = hb + (size_t)row * D_MODEL;
  for (int i = threadIdx.x; i < D_MODEL; i += 256)
    q[i] = f2bf((p[i] - mu) * inv * gamma[i] + beta[i]);
}

// conv+silu: read xb fp32 [NTOK][2048], write u bf16
__global__ __launch_bounds__(256)
void conv_silu_k(const float* __restrict__ xb, const float* __restrict__ cw,
                 const float* __restrict__ cb, unsigned short* __restrict__ ub)
{
  const int idx = blockIdx.x * 256 + threadIdx.x;
  const int d  = idx & (D_INNER - 1);
  const int bt = idx >> 11;
  const int t  = bt & (SEQ - 1);
  float acc = cb[d];
  const float* base = xb + (size_t)bt * D_INNER + d;
  #pragma unroll
  for (int k = 0; k < D_CONV; ++k) {
    int tt = t + k - (D_CONV - 1);
    if (tt >= 0) acc = fmaf(cw[d*D_CONV + k], base[(ptrdiff_t)(k - (D_CONV-1)) * D_INNER], acc);
  }
  ub[idx] = f2bf(siluf(acc));
}

// ---- chunk-parallel scan; BC compact [NTOK][32] fp32 ----
__global__ __launch_bounds__(256)
void scan_p1(const float* __restrict__ dtb, const unsigned short* __restrict__ ub,
             const float* __restrict__ BC, const float* __restrict__ A_log,
             float* __restrict__ summ)
{
  const int bid = blockIdx.x;
  const int b = bid >> 7;
  const int c = (bid >> 3) & (NCHUNK - 1);
  const int d = ((bid & 7) << 8) + threadIdx.x;
  float A[D_STATE], hl[D_STATE];
  #pragma unroll
  for (int n = 0; n < D_STATE; ++n) { A[n] = -__expf(A_log[d*D_STATE + n]); hl[n] = 0.f; }
  float dtsum = 0.f;
  const size_t row0 = (size_t)b * SEQ + (size_t)c * CHUNK;
  float dtv = dtb[row0*D_INNER + d];
  float uv  = bf2f(ub[row0*D_INNER + d]);
  float Bv[D_STATE];
  #pragma unroll
  for (int n = 0; n < D_STATE; ++n) Bv[n] = BC[row0*32 + n];
  for (int t = 0; t < CHUNK; ++t) {
    const size_t rn = row0 + ((t+1 < CHUNK) ? (t+1) : t);  // clamped prefetch
    float ndt = dtb[rn*D_INNER + d];
    float nu  = bf2f(ub[rn*D_INNER + d]);
    float nB[D_STATE];
    #pragma unroll
    for (int n = 0; n < D_STATE; ++n) nB[n] = BC[rn*32 + n];
    const float du = dtv * uv;
    dtsum += dtv;
    #pragma unroll
    for (int n = 0; n < D_STATE; ++n) {
      float dA = __expf(dtv * A[n]);
      hl[n] = fmaf(dA, hl[n], du * Bv[n]);
    }
    dtv = ndt; uv = nu;
    #pragma unroll
    for (int n = 0; n < D_STATE; ++n) Bv[n] = nB[n];
  }
  float* s = summ + (((size_t)b*NCHUNK + c)*32)*D_INNER + d;
  #pragma unroll
  for (int n = 0; n < D_STATE; ++n) {
    s[(size_t)n*D_INNER]      = __expf(A[n] * dtsum);
    s[(size_t)(16+n)*D_INNER] = hl[n];
  }
}

__global__ __launch_bounds__(256)
void scan_p2(float* __restrict__ summ, const float* __restrict__ h0,
             float* __restrict__ outH)
{
  const int b = blockIdx.x >> 3;
  const int d = ((blockIdx.x & 7) << 8) + threadIdx.x;
  float h[D_STATE];
  #pragma unroll
  for (int n = 0; n < D_STATE; ++n) h[n] = h0[((size_t)b*D_INNER + d)*D_STATE + n];
  float pv[D_STATE], lv[D_STATE];
  float* s0 = summ + (((size_t)b*NCHUNK + 0)*32)*D_INNER + d;
  #pragma unroll
  for (int n = 0; n < D_STATE; ++n) { pv[n] = s0[(size_t)n*D_INNER]; lv[n] = s0[(size_t)(16+n)*D_INNER]; }
  for (int c = 0; c < NCHUNK; ++c) {
    float* s = summ + (((size_t)b*NCHUNK + c)*32)*D_INNER + d;
    const int cn = (c+1 < NCHUNK) ? (c+1) : c;
    float* sn = summ + (((size_t)b*NCHUNK + cn)*32)*D_INNER + d;
    float np[D_STATE], nl[D_STATE];
    #pragma unroll
    for (int n = 0; n < D_STATE; ++n) { np[n] = sn[(size_t)n*D_INNER]; nl[n] = sn[(size_t)(16+n)*D_INNER]; }
    #pragma unroll
    for (int n = 0; n < D_STATE; ++n) {
      s[(size_t)n*D_INNER] = h[n];            // start state for chunk c
      h[n] = fmaf(pv[n], h[n], lv[n]);
      pv[n] = np[n]; lv[n] = nl[n];
    }
  }
  #pragma unroll
  for (int n = 0; n < D_STATE; ++n)
    outH[((size_t)b*D_INNER + d)*D_STATE + n] = h[n];
}

__global__ __launch_bounds__(256)
void scan_p3(const float* __restrict__ dtb, const unsigned short* __restrict__ ub,
             const unsigned short* __restrict__ zbh, const float* __restrict__ BC,
             const float* __restrict__ A_log, const float* __restrict__ D_skip,
             const float* __restrict__ summ, unsigned short* __restrict__ yb)
{
  const int bid = blockIdx.x;
  const int b = bid >> 7;
  const int c = (bid >> 3) & (NCHUNK - 1);
  const int d = ((bid & 7) << 8) + threadIdx.x;
  float A[D_STATE], h[D_STATE];
  const float* s = summ + (((size_t)b*NCHUNK + c)*32)*D_INNER + d;
  #pragma unroll
  for (int n = 0; n < D_STATE; ++n) {
    A[n] = -__expf(A_log[d*D_STATE + n]);
    h[n] = s[(size_t)n*D_INNER];
  }
  const float Ds = D_skip[d];
  const size_t row0 = (size_t)b * SEQ + (size_t)c * CHUNK;
  float dtv = dtb[row0*D_INNER + d];
  float uv  = bf2f(ub[row0*D_INNER + d]);
  float zv  = bf2f(zbh[row0*D_INNER + d]);
  float Bv[D_STATE], Cv[D_STATE];
  #pragma unroll
  for (int n = 0; n < D_STATE; ++n) { Bv[n] = BC[row0*32 + n]; Cv[n] = BC[row0*32 + 16 + n]; }
  for (int t = 0; t < CHUNK; ++t) {
    const size_t r = row0 + t;
    const size_t rn = row0 + ((t+1 < CHUNK) ? (t+1) : t);
    float ndt = dtb[rn*D_INNER + d];
    float nu  = bf2f(ub[rn*D_INNER + d]);
    float nz  = bf2f(zbh[rn*D_INNER + d]);
    float nB[D_STATE], nC[D_STATE];
    #pragma unroll
    for (int n = 0; n < D_STATE; ++n) { nB[n] = BC[rn*32 + n]; nC[n] = BC[rn*32 + 16 + n]; }
    const float du = dtv * uv;
    float y = 0.f;
    #pragma unroll
    for (int n = 0; n < D_STATE; ++n) {
      float dA = __expf(dtv * A[n]);
      h[n] = fmaf(dA, h[n], du * Bv[n]);
      y = fmaf(h[n], Cv[n], y);
    }
    y = fmaf(uv, Ds, y);
    yb[r*D_INNER + d] = f2bf(y * siluf(zv));
    dtv = ndt; uv = nu; zv = nz;
    #pragma unroll
    for (int n = 0; n < D_STATE; ++n) { Bv[n] = nB[n]; Cv[n] = nC[n]; }
  }
}

extern "C" void kernel_launch(void* const* d_in, const int* in_sizes, int n_in,
                              void* d_out, int out_size, void* d_ws, size_t ws_size,
                              hipStream_t stream) {
  const float* x          = (const float*)d_in[0];
  const float* h0         = (const float*)d_in[1];
  const float* W_in_wrap  = (const float*)d_in[2];
  const float* b_in_wrap  = (const float*)d_in[3];
  const float* ln_g       = (const float*)d_in[4];
  const float* ln_b       = (const float*)d_in[5];
  const float* W_in       = (const float*)d_in[6];
  const float* conv_w     = (const float*)d_in[7];
  const float* conv_b     = (const float*)d_in[8];
  const float* W_x        = (const float*)d_in[9];
  const float* W_dt       = (const float*)d_in[10];
  const float* b_dt       = (const float*)d_in[11];
  const float* A_log      = (const float*)d_in[12];
  const float* D_skip     = (const float*)d_in[13];
  const float* W_out      = (const float*)d_in[14];
  const float* W_out_wrap = (const float*)d_in[15];
  const float* b_out_wrap = (const float*)d_in[16];

  float* out  = (float*)d_out;                       // (B,T,OUT_DIM)
  float* outH = out + (size_t)NTOK * OUT_DIM;        // (B,D_INNER,D_STATE)

  char* ws = (char*)d_ws;
  auto at = [&](size_t kb){ return (void*)(ws + kb*1024); };
  float*          hbuf = (float*)at(0);        // 8 MB fp32 h (then summ)
  float*          summ = hbuf;
  float*          xb   = (float*)at(8192);     // 16 MB fp32 x_branch (then dtb)
  float*          dtb  = xb;
  unsigned short* zbh  = (unsigned short*)at(24576);  // 4 MB bf16 z
  unsigned short* ub   = (unsigned short*)at(40960);  // 8 MB bf16 u (xb16 early)
  unsigned short* xb16 = ub;                          // 1 MB bf16 x-cast (dead before conv)
  unsigned short* gb   = (unsigned short*)at(49152);  // 8 MB bf16 gate (WiwT early; yb later)
  unsigned short* WiwT = gb;                          // 512 KB (dead before proj)
  unsigned short* yb   = gb;
  unsigned short* hb   = (unsigned short*)at(57344);  // 4 MB bf16 h_ln (then tmpb)
  unsigned short* tmpb = hb;
  float*          BC   = (float*)at(61440);    // 256 KB fp32 [NTOK][32]
  unsigned short* WinT = (unsigned short*)at(61696);  // 8 MB   [4096][1024]
  unsigned short* WxT  = (unsigned short*)at(69888);  // 8.5 MB [2176pad][2048]
  unsigned short* WdtT = (unsigned short*)at(78592);  // 8 MB   [2048][2048]
  unsigned short* WoutT= (unsigned short*)at(86784);  // 4 MB   [1024][2048]
  unsigned short* WwrT = (unsigned short*)at(90880);  // 512 KB [256][1024]  (ends 89.25 MB)

  dim3 blk(256);
  // 0) fused prep: all weight transposes + x cast + WxT pad zero (1 launch)
  prep_k<<<dim3(15520), blk, 0, stream>>>(x, W_in_wrap, W_in, W_x, W_dt, W_out, W_out_wrap,
                                          xb16, WiwT, WinT, WxT, WdtT, WoutT, WwrT);
  // 1) h = x @ W_in_wrap + b_in_wrap  (512 blocks)
  gemm_bf16<64,64,0><<<dim3(1024/64, NTOK/64), blk, 0, stream>>>(xb16, WiwT, NTOK, 1024, 256,
                                                                 256, 256, b_in_wrap, hbuf, nullptr);
  // 2) LayerNorm -> bf16
  ln_k<<<dim3(NTOK), blk, 0, stream>>>(hbuf, ln_g, ln_b, hb);
  // 3) xz = h @ W_in -> xb fp32 | z bf16   (2048 blocks)
  gemm_bf16<64,64,3><<<dim3(4096/64, NTOK/64), blk, 0, stream>>>(hb, WinT, NTOK, 4096, 1024,
                                                                 1024, 1024, nullptr, xb, zbh);
  // 4) u = silu(conv(xb)) -> bf16
  conv_silu_k<<<dim3(NTOK*D_INNER/256), blk, 0, stream>>>(xb, conv_w, conv_b, ub);
  // 5) proj = u @ W_x -> BC fp32 [.,32] | g bf16 [.,2048]  (1056 blocks)
  gemm_bf16<64,64,4><<<dim3(2112/64, NTOK/64), blk, 0, stream>>>(ub, WxT, NTOK, PROJ_N, 2048,
                                                                 2048, 2048, nullptr, BC, gb);
  // 6) dt = softplus(g @ W_dt + b_dt) -> fp32 (over xb)   (1024 blocks)
  gemm_bf16<64,64,1><<<dim3(2048/64, NTOK/64), blk, 0, stream>>>(gb, WdtT, NTOK, 2048, 2048,
                                                                 2048, 2048, b_dt, dtb, nullptr);
  // 7) chunk-parallel scan
  scan_p1<<<dim3(BATCH*NCHUNK*(D_INNER/256)), blk, 0, stream>>>(dtb, ub, BC, A_log, summ);
  scan_p2<<<dim3(BATCH*(D_INNER/256)), blk, 0, stream>>>(summ, h0, outH);
  scan_p3<<<dim3(BATCH*NCHUNK*(D_INNER/256)), blk, 0, stream>>>(dtb, ub, zbh, BC, A_log, D_skip, summ, yb);
  // 8) tmp = y @ W_out -> bf16 (over hb)    (512 blocks)
  gemm_bf16<64,64,2><<<dim3(1024/64, NTOK/64), blk, 0, stream>>>(yb, WoutT, NTOK, 1024, 2048,
                                                                 2048, 2048, nullptr, tmpb, nullptr);
  // 9) out = tmp @ W_out_wrap + b_out_wrap (fp32 out, 128 blocks)
  gemm_bf16<64,64,0><<<dim3(256/64, NTOK/64), blk, 0, stream>>>(tmpb, WwrT, NTOK, 256, 1024,
                                                                1024, 1024, b_out_wrap, out, nullptr);
}

// Round 8
// 295.619 us; speedup vs baseline: 1.0685x; 1.0685x over previous
//
#include <hip/hip_runtime.h>
#include <cstddef>
#include <cstdint>

#define D_MODEL 1024
#define D_STATE 16
#define D_CONV 4
#define D_INNER 2048
#define IN_DIM 256
#define OUT_DIM 256
#define BATCH 2
#define SEQ 1024
#define NTOK (BATCH*SEQ)
#define PROJ_N (2*D_STATE + D_INNER) // 2080
#define CHUNK 64
#define NCHUNK (SEQ/CHUNK)           // 16

typedef __attribute__((ext_vector_type(8))) short bf16x8;
typedef __attribute__((ext_vector_type(16))) float f32x16;

__device__ __forceinline__ float siluf(float x){ return x / (1.f + __expf(-x)); }

__device__ __forceinline__ unsigned short f2bf(float f) {
  uint32_t x = __float_as_uint(f);
  uint32_t r = x + 0x7fffu + ((x >> 16) & 1u);
  return (unsigned short)(r >> 16);
}
__device__ __forceinline__ float bf2f(unsigned short u) {
  return __uint_as_float(((uint32_t)u) << 16);
}

__device__ __forceinline__ void gload16(const void* g, void* l) {
  __builtin_amdgcn_global_load_lds((const __attribute__((address_space(1))) void*)g,
                                   (__attribute__((address_space(3))) void*)l, 16, 0, 0);
}

template<int N> __device__ __forceinline__ void waitvm() {
  if constexpr (N == 0) asm volatile("s_waitcnt vmcnt(0)" ::: "memory");
  else if constexpr (N == 2) asm volatile("s_waitcnt vmcnt(2)" ::: "memory");
  else if constexpr (N == 3) asm volatile("s_waitcnt vmcnt(3)" ::: "memory");
  else if constexpr (N == 4) asm volatile("s_waitcnt vmcnt(4)" ::: "memory");
  else if constexpr (N == 6) asm volatile("s_waitcnt vmcnt(6)" ::: "memory");
  else                       asm volatile("s_waitcnt vmcnt(8)" ::: "memory");
}
template<int N> __device__ __forceinline__ void waitlgkm() {
  if constexpr (N == 0)      asm volatile("s_waitcnt lgkmcnt(0)" ::: "memory");
  else if constexpr (N == 4) asm volatile("s_waitcnt lgkmcnt(4)" ::: "memory");
  else if constexpr (N == 6) asm volatile("s_waitcnt lgkmcnt(6)" ::: "memory");
  else                       asm volatile("s_waitcnt lgkmcnt(8)" ::: "memory");
}

// ------------- fused weight prep: 6 transposes + x cast + WxT pad zero -------
__device__ __forceinline__ void tc_tile(float (*tile)[33], const float* __restrict__ in,
                                        unsigned short* __restrict__ out,
                                        int R, int C, int tcx, int tcy, int tid)
{
  const int bc = tcx * 32, br = tcy * 32;
  const int tx = tid & 31, ty = tid >> 5;
  #pragma unroll
  for (int i = 0; i < 4; ++i) {
    int r = ty + i*8;
    tile[r][tx] = in[(size_t)(br + r)*C + bc + tx];
  }
  __syncthreads();
  const int otx = tid & 7, oty = tid >> 3;
  ushort4 v;
  v.x = f2bf(tile[otx*4+0][oty]);
  v.y = f2bf(tile[otx*4+1][oty]);
  v.z = f2bf(tile[otx*4+2][oty]);
  v.w = f2bf(tile[otx*4+3][oty]);
  *(ushort4*)&out[(size_t)(bc + oty)*R + br + otx*4] = v;
}

__global__ __launch_bounds__(256)
void prep_k(const float* __restrict__ x, const float* __restrict__ Wiw,
            const float* __restrict__ Win, const float* __restrict__ Wx,
            const float* __restrict__ Wdt, const float* __restrict__ Wout,
            const float* __restrict__ Wwr,
            unsigned short* __restrict__ xb16, unsigned short* __restrict__ WiwT,
            unsigned short* __restrict__ WinT, unsigned short* __restrict__ WxT,
            unsigned short* __restrict__ WdtT, unsigned short* __restrict__ WoutT,
            unsigned short* __restrict__ WwrT)
{
  __shared__ float tile[32][33];
  const int tid = threadIdx.x;
  int id = blockIdx.x;
  if (id < 4096)  { tc_tile(tile, Win,  WinT,  1024, 4096, id % 128, id / 128, tid); return; }
  id -= 4096;
  if (id < 4160)  { tc_tile(tile, Wx,   WxT,   2048, 2080, id % 65,  id / 65,  tid); return; }
  id -= 4160;
  if (id < 4096)  { tc_tile(tile, Wdt,  WdtT,  2048, 2048, id % 64,  id / 64,  tid); return; }
  id -= 4096;
  if (id < 2048)  { tc_tile(tile, Wout, WoutT, 2048, 1024, id % 32,  id / 32,  tid); return; }
  id -= 2048;
  if (id < 256)   { tc_tile(tile, Wwr,  WwrT,  1024, 256,  id % 8,   id / 8,   tid); return; }
  id -= 256;
  if (id < 256)   { tc_tile(tile, Wiw,  WiwT,  256,  1024, id % 32,  id / 32,  tid); return; }
  id -= 256;
  if (id < 512) {                                  // cast x -> bf16 (float4)
    int i = id * 256 + tid;                        // < 131072 = NTOK*IN_DIM/4
    float4 v = ((const float4*)x)[i];
    ushort4 o;
    o.x = f2bf(v.x); o.y = f2bf(v.y); o.z = f2bf(v.z); o.w = f2bf(v.w);
    ((ushort4*)xb16)[i] = o;
    return;
  }
  id -= 512;
  {                                                // zero WxT pad rows 2080..2175
    unsigned short* p = WxT + (size_t)(2080 + id) * 2048 + tid * 8;
    ushort4 z = {0,0,0,0};
    *(ushort4*)p = z; *(ushort4*)(p + 4) = z;
  }
}

// ---------------- bf16 MFMA GEMM, register-pipelined fragments ---------------
// B pre-transposed: B[N][K] row-major. 4-buffer LDS, depth-2 staging lookahead,
// fragment ds_reads issued ONE STEP AHEAD into ping-pong register sets with a
// counted lgkmcnt — ds_read latency overlaps the previous step's MFMA+barrier.
// Requires (K/32) % 4 == 0, NT >= 8.
// MODE: 0 f32 out (+bias); 1 softplus(v+bias) f32; 2 bf16 out;
//       3 split xz -> out0=xb fp32 [M][2048] (c<2048), out1=zb bf16 [M][2048];
//       4 proj -> out0=BC fp32 [M][32] (c<32), out1=g bf16 [M][2048]
template<int BM, int BN, int MODE>
__global__ __launch_bounds__(256)
void gemm_bf16(const unsigned short* __restrict__ A, const unsigned short* __restrict__ B,
               int M, int N, int K, int lda, int ldb,
               const float* __restrict__ bias,
               void* __restrict__ out0, void* __restrict__ out1)
{
  constexpr int FM = BM / 64;           // 32x32 frags per wave, M dir
  constexpr int FN = BN / 64;
  constexpr int ROWS = BM + BN;
  constexpr int G = ROWS / 16;          // 16-row staging groups
  constexpr int IPW = G / 4;            // gload16 issues per wave per stage
  constexpr int NR = 2*(FM+FN);         // ds_read_b128 per step per lane
  __shared__ __align__(1024) unsigned short S[4][ROWS*32];

  const int tid = threadIdx.x;
  const int lane = tid & 63, w = tid >> 6;
  const int row0 = blockIdx.y * BM, col0 = blockIdx.x * BN;
  const int wr = (w >> 1) * (BM/2), wc = (w & 1) * (BN/2);
  const int lrq = lane >> 2;     // row within 16-row staging group
  const int lg  = lane & 3;      // dest granule slot
  const int l31 = lane & 31, lh = lane >> 5;

  // K-invariant fragment LDS offsets; swizzle f(r) = (r>>1)&3
  int afo[FM][2], bfo[FN][2];
  #pragma unroll
  for (int fi = 0; fi < FM; ++fi)
    #pragma unroll
    for (int h = 0; h < 2; ++h) {
      const int r = wr + fi*32 + l31;
      const int slot = (2*h + lh) ^ ((r >> 1) & 3);
      afo[fi][h] = (r>>4)*512 + (r&15)*32 + slot*8;
    }
  #pragma unroll
  for (int fj = 0; fj < FN; ++fj)
    #pragma unroll
    for (int h = 0; h < 2; ++h) {
      const int r = wc + fj*32 + l31;
      const int slot = (2*h + lh) ^ ((r >> 1) & 3);
      bfo[fj][h] = BM*32 + (r>>4)*512 + (r&15)*32 + slot*8;
    }

  // staging: incremented global pointers + fixed LDS dests
  const unsigned short* src[IPW];
  int ldso[IPW];
  #pragma unroll
  for (int i = 0; i < IPW; ++i) {
    const int base = (w + i*4) * 16;             // wave-uniform group base row
    const int lr = base + lrq;
    const int gs = lg ^ ((lr >> 1) & 3);         // matching involution
    ldso[i] = base * 32;
    src[i] = (base < BM) ? A + (size_t)(row0 + lr) * lda + gs*8
                         : B + (size_t)(col0 + lr - BM) * ldb + gs*8;
  }

  f32x16 acc[FM][FN];
  #pragma unroll
  for (int i=0;i<FM;i++)
    #pragma unroll
    for (int j=0;j<FN;j++)
      #pragma unroll
      for (int q=0;q<16;q++) acc[i][j][q] = 0.f;

  const int NT = K >> 5;

  auto stage = [&](int buf) {
    #pragma unroll
    for (int i = 0; i < IPW; ++i) {
      gload16(src[i], &S[buf][ldso[i]]);
      src[i] += 32;                              // next K-tile
    }
  };

  bf16x8 afA[FM][2], bfA[FN][2], afB[FM][2], bfB[FN][2];
  auto readf = [&](int buf, bf16x8 (&af)[FM][2], bf16x8 (&bf)[FN][2]) {
    const unsigned short* Sb = &S[buf][0];
    #pragma unroll
    for (int fi = 0; fi < FM; ++fi) {
      af[fi][0] = *(const bf16x8*)(Sb + afo[fi][0]);
      af[fi][1] = *(const bf16x8*)(Sb + afo[fi][1]);
    }
    #pragma unroll
    for (int fj = 0; fj < FN; ++fj) {
      bf[fj][0] = *(const bf16x8*)(Sb + bfo[fj][0]);
      bf[fj][1] = *(const bf16x8*)(Sb + bfo[fj][1]);
    }
  };
  auto domfma = [&](bf16x8 (&af)[FM][2], bf16x8 (&bf)[FN][2]) {
    #pragma unroll
    for (int h = 0; h < 2; ++h)
      #pragma unroll
      for (int fi = 0; fi < FM; ++fi)
        #pragma unroll
        for (int fj = 0; fj < FN; ++fj)
          acc[fi][fj] = __builtin_amdgcn_mfma_f32_32x32x16_bf16(af[fi][h], bf[fj][h], acc[fi][fj], 0, 0, 0);
  };

  // prologue: 3 buffers staged; step-0 fragments into A regs
  stage(0); stage(1); stage(2);
  waitvm<2*IPW>();
  __builtin_amdgcn_s_barrier();
  asm volatile("" ::: "memory");
  readf(0, afA, bfA);
  waitlgkm<0>();

  for (int kt = 0; kt < NT; kt += 4) {
    #pragma unroll
    for (int jj = 0; jj < 4; ++jj) {
      const int j = kt + jj;
      if (j + 1 < NT) {
        if (j + 2 < NT) waitvm<IPW>(); else waitvm<0>();   // buffer j+1 landed
        __builtin_amdgcn_s_barrier();
        asm volatile("" ::: "memory");
        if (j + 3 < NT) stage((jj + 3) & 3);
        if ((jj & 1) == 0) readf((jj + 1) & 3, afB, bfB);  // prefetch j+1 frags
        else               readf((jj + 1) & 3, afA, bfA);
        waitlgkm<NR>();                                    // step-j frags landed
      } else {
        waitlgkm<0>();                                     // last step's frags
      }
      __builtin_amdgcn_sched_barrier(0);
      if ((jj & 1) == 0) domfma(afA, bfA);
      else               domfma(afB, bfB);
      __builtin_amdgcn_sched_barrier(0);
      asm volatile("" ::: "memory");
    }
  }

  // epilogue: C/D layout col=lane&31, row=(reg&3)+8*(reg>>2)+4*(lane>>5)
  #pragma unroll
  for (int fi=0; fi<FM; fi++){
    #pragma unroll
    for (int fj=0; fj<FN; fj++){
      const int c = col0 + wc + fj*32 + l31;
      #pragma unroll
      for (int reg=0; reg<16; reg++){
        const int r = row0 + wr + fi*32 + 4*lh + (reg&3) + 8*(reg>>2);
        float v = acc[fi][fj][reg];
        if constexpr (MODE == 0) {
          if (c < N) ((float*)out0)[(size_t)r*N + c] = bias ? v + bias[c] : v;
        } else if constexpr (MODE == 1) {
          if (c < N) { v += bias[c]; v = (v > 20.f) ? v : log1pf(__expf(v));
                       ((float*)out0)[(size_t)r*N + c] = v; }
        } else if constexpr (MODE == 2) {
          if (c < N) ((unsigned short*)out0)[(size_t)r*N + c] = f2bf(v);
        } else if constexpr (MODE == 3) {
          if (c < 2048) ((float*)out0)[(size_t)r*2048 + c] = v;
          else          ((unsigned short*)out1)[(size_t)r*2048 + (c - 2048)] = f2bf(v);
        } else {
          if (c < 32) ((float*)out0)[(size_t)r*32 + c] = v;
          else if (c < N) ((unsigned short*)out1)[(size_t)r*2048 + (c - 32)] = f2bf(v);
        }
      }
    }
  }
}

// LayerNorm: read fp32 h, write bf16
__global__ __launch_bounds__(256)
void ln_k(const float* __restrict__ h, const float* __restrict__ gamma,
          const float* __restrict__ beta, unsigned short* __restrict__ hb)
{
  const int row = blockIdx.x;
  const float* p = h + (size_t)row * D_MODEL;
  float s = 0.f, s2 = 0.f;
  for (int i = threadIdx.x; i < D_MODEL; i += 256) { float v = p[i]; s += v; s2 += v*v; }
  #pragma unroll
  for (int off = 32; off; off >>= 1) { s += __shfl_down(s, off, 64); s2 += __shfl_down(s2, off, 64); }
  __shared__ float ss[4], ss2[4];
  __shared__ float smu, sinv;
  const int wid = threadIdx.x >> 6;
  if ((threadIdx.x & 63) == 0) { ss[wid] = s; ss2[wid] = s2; }
  __syncthreads();
  if (threadIdx.x == 0) {
    float S = ss[0]+ss[1]+ss[2]+ss[3];
    float S2 = ss2[0]+ss2[1]+ss2[2]+ss2[3];
    float mu = S * (1.f / D_MODEL);
    float var = S2 * (1.f / D_MODEL) - mu * mu;
    smu = mu; sinv = rsqrtf(var + 1e-5f);
  }
  __syncthreads();
  const float mu = smu, inv = sinv;
  unsigned short* q = hb + (size_t)row * D_MODEL;
  for (int i = threadIdx.x; i < D_MODEL; i += 256)
    q[i] = f2bf((p[i] - mu) * inv * gamma[i] + beta[i]);
}

// conv+silu: read xb fp32 [NTOK][2048], write u bf16
__global__ __launch_bounds__(256)
void conv_silu_k(const float* __restrict__ xb, const float* __restrict__ cw,
                 const float* __restrict__ cb, unsigned short* __restrict__ ub)
{
  const int idx = blockIdx.x * 256 + threadIdx.x;
  const int d  = idx & (D_INNER - 1);
  const int bt = idx >> 11;
  const int t  = bt & (SEQ - 1);
  float acc = cb[d];
  const float* base = xb + (size_t)bt * D_INNER + d;
  #pragma unroll
  for (int k = 0; k < D_CONV; ++k) {
    int tt = t + k - (D_CONV - 1);
    if (tt >= 0) acc = fmaf(cw[d*D_CONV + k], base[(ptrdiff_t)(k - (D_CONV-1)) * D_INNER], acc);
  }
  ub[idx] = f2bf(siluf(acc));
}

// ---- chunk-parallel scan; BC compact [NTOK][32] fp32 ----
__global__ __launch_bounds__(256)
void scan_p1(const float* __restrict__ dtb, const unsigned short* __restrict__ ub,
             const float* __restrict__ BC, const float* __restrict__ A_log,
             float* __restrict__ summ)
{
  const int bid = blockIdx.x;
  const int b = bid >> 7;
  const int c = (bid >> 3) & (NCHUNK - 1);
  const int d = ((bid & 7) << 8) + threadIdx.x;
  float A[D_STATE], hl[D_STATE];
  #pragma unroll
  for (int n = 0; n < D_STATE; ++n) { A[n] = -__expf(A_log[d*D_STATE + n]); hl[n] = 0.f; }
  float dtsum = 0.f;
  const size_t row0 = (size_t)b * SEQ + (size_t)c * CHUNK;
  float dtv = dtb[row0*D_INNER + d];
  float uv  = bf2f(ub[row0*D_INNER + d]);
  float Bv[D_STATE];
  #pragma unroll
  for (int n = 0; n < D_STATE; ++n) Bv[n] = BC[row0*32 + n];
  for (int t = 0; t < CHUNK; ++t) {
    const size_t rn = row0 + ((t+1 < CHUNK) ? (t+1) : t);  // clamped prefetch
    float ndt = dtb[rn*D_INNER + d];
    float nu  = bf2f(ub[rn*D_INNER + d]);
    float nB[D_STATE];
    #pragma unroll
    for (int n = 0; n < D_STATE; ++n) nB[n] = BC[rn*32 + n];
    const float du = dtv * uv;
    dtsum += dtv;
    #pragma unroll
    for (int n = 0; n < D_STATE; ++n) {
      float dA = __expf(dtv * A[n]);
      hl[n] = fmaf(dA, hl[n], du * Bv[n]);
    }
    dtv = ndt; uv = nu;
    #pragma unroll
    for (int n = 0; n < D_STATE; ++n) Bv[n] = nB[n];
  }
  float* s = summ + (((size_t)b*NCHUNK + c)*32)*D_INNER + d;
  #pragma unroll
  for (int n = 0; n < D_STATE; ++n) {
    s[(size_t)n*D_INNER]      = __expf(A[n] * dtsum);
    s[(size_t)(16+n)*D_INNER] = hl[n];
  }
}

__global__ __launch_bounds__(256)
void scan_p2(float* __restrict__ summ, const float* __restrict__ h0,
             float* __restrict__ outH)
{
  const int b = blockIdx.x >> 3;
  const int d = ((blockIdx.x & 7) << 8) + threadIdx.x;
  float h[D_STATE];
  #pragma unroll
  for (int n = 0; n < D_STATE; ++n) h[n] = h0[((size_t)b*D_INNER + d)*D_STATE + n];
  float pv[D_STATE], lv[D_STATE];
  float* s0 = summ + (((size_t)b*NCHUNK + 0)*32)*D_INNER + d;
  #pragma unroll
  for (int n = 0; n < D_STATE; ++n) { pv[n] = s0[(size_t)n*D_INNER]; lv[n] = s0[(size_t)(16+n)*D_INNER]; }
  for (int c = 0; c < NCHUNK; ++c) {
    float* s = summ + (((size_t)b*NCHUNK + c)*32)*D_INNER + d;
    const int cn = (c+1 < NCHUNK) ? (c+1) : c;
    float* sn = summ + (((size_t)b*NCHUNK + cn)*32)*D_INNER + d;
    float np[D_STATE], nl[D_STATE];
    #pragma unroll
    for (int n = 0; n < D_STATE; ++n) { np[n] = sn[(size_t)n*D_INNER]; nl[n] = sn[(size_t)(16+n)*D_INNER]; }
    #pragma unroll
    for (int n = 0; n < D_STATE; ++n) {
      s[(size_t)n*D_INNER] = h[n];            // start state for chunk c
      h[n] = fmaf(pv[n], h[n], lv[n]);
      pv[n] = np[n]; lv[n] = nl[n];
    }
  }
  #pragma unroll
  for (int n = 0; n < D_STATE; ++n)
    outH[((size_t)b*D_INNER + d)*D_STATE + n] = h[n];
}

__global__ __launch_bounds__(256)
void scan_p3(const float* __restrict__ dtb, const unsigned short* __restrict__ ub,
             const unsigned short* __restrict__ zbh, const float* __restrict__ BC,
             const float* __restrict__ A_log, const float* __restrict__ D_skip,
             const float* __restrict__ summ, unsigned short* __restrict__ yb)
{
  const int bid = blockIdx.x;
  const int b = bid >> 7;
  const int c = (bid >> 3) & (NCHUNK - 1);
  const int d = ((bid & 7) << 8) + threadIdx.x;
  float A[D_STATE], h[D_STATE];
  const float* s = summ + (((size_t)b*NCHUNK + c)*32)*D_INNER + d;
  #pragma unroll
  for (int n = 0; n < D_STATE; ++n) {
    A[n] = -__expf(A_log[d*D_STATE + n]);
    h[n] = s[(size_t)n*D_INNER];
  }
  const float Ds = D_skip[d];
  const size_t row0 = (size_t)b * SEQ + (size_t)c * CHUNK;
  float dtv = dtb[row0*D_INNER + d];
  float uv  = bf2f(ub[row0*D_INNER + d]);
  float zv  = bf2f(zbh[row0*D_INNER + d]);
  float Bv[D_STATE], Cv[D_STATE];
  #pragma unroll
  for (int n = 0; n < D_STATE; ++n) { Bv[n] = BC[row0*32 + n]; Cv[n] = BC[row0*32 + 16 + n]; }
  for (int t = 0; t < CHUNK; ++t) {
    const size_t r = row0 + t;
    const size_t rn = row0 + ((t+1 < CHUNK) ? (t+1) : t);
    float ndt = dtb[rn*D_INNER + d];
    float nu  = bf2f(ub[rn*D_INNER + d]);
    float nz  = bf2f(zbh[rn*D_INNER + d]);
    float nB[D_STATE], nC[D_STATE];
    #pragma unroll
    for (int n = 0; n < D_STATE; ++n) { nB[n] = BC[rn*32 + n]; nC[n] = BC[rn*32 + 16 + n]; }
    const float du = dtv * uv;
    float y = 0.f;
    #pragma unroll
    for (int n = 0; n < D_STATE; ++n) {
      float dA = __expf(dtv * A[n]);
      h[n] = fmaf(dA, h[n], du * Bv[n]);
      y = fmaf(h[n], Cv[n], y);
    }
    y = fmaf(uv, Ds, y);
    yb[r*D_INNER + d] = f2bf(y * siluf(zv));
    dtv = ndt; uv = nu; zv = nz;
    #pragma unroll
    for (int n = 0; n < D_STATE; ++n) { Bv[n] = nB[n]; Cv[n] = nC[n]; }
  }
}

extern "C" void kernel_launch(void* const* d_in, const int* in_sizes, int n_in,
                              void* d_out, int out_size, void* d_ws, size_t ws_size,
                              hipStream_t stream) {
  const float* x          = (const float*)d_in[0];
  const float* h0         = (const float*)d_in[1];
  const float* W_in_wrap  = (const float*)d_in[2];
  const float* b_in_wrap  = (const float*)d_in[3];
  const float* ln_g       = (const float*)d_in[4];
  const float* ln_b       = (const float*)d_in[5];
  const float* W_in       = (const float*)d_in[6];
  const float* conv_w     = (const float*)d_in[7];
  const float* conv_b     = (const float*)d_in[8];
  const float* W_x        = (const float*)d_in[9];
  const float* W_dt       = (const float*)d_in[10];
  const float* b_dt       = (const float*)d_in[11];
  const float* A_log      = (const float*)d_in[12];
  const float* D_skip     = (const float*)d_in[13];
  const float* W_out      = (const float*)d_in[14];
  const float* W_out_wrap = (const float*)d_in[15];
  const float* b_out_wrap = (const float*)d_in[16];

  float* out  = (float*)d_out;                       // (B,T,OUT_DIM)
  float* outH = out + (size_t)NTOK * OUT_DIM;        // (B,D_INNER,D_STATE)

  char* ws = (char*)d_ws;
  auto at = [&](size_t kb){ return (void*)(ws + kb*1024); };
  float*          hbuf = (float*)at(0);        // 8 MB fp32 h (then summ)
  float*          summ = hbuf;
  float*          xb   = (float*)at(8192);     // 16 MB fp32 x_branch (then dtb)
  float*          dtb  = xb;
  unsigned short* zbh  = (unsigned short*)at(24576);  // 4 MB bf16 z
  unsigned short* ub   = (unsigned short*)at(40960);  // 8 MB bf16 u (xb16 early)
  unsigned short* xb16 = ub;                          // 1 MB bf16 x-cast (dead before conv)
  unsigned short* gb   = (unsigned short*)at(49152);  // 8 MB bf16 gate (WiwT early; yb later)
  unsigned short* WiwT = gb;                          // 512 KB (dead before proj)
  unsigned short* yb   = gb;
  unsigned short* hb   = (unsigned short*)at(57344);  // 4 MB bf16 h_ln (then tmpb)
  unsigned short* tmpb = hb;
  float*          BC   = (float*)at(61440);    // 256 KB fp32 [NTOK][32]
  unsigned short* WinT = (unsigned short*)at(61696);  // 8 MB   [4096][1024]
  unsigned short* WxT  = (unsigned short*)at(69888);  // 8.5 MB [2176pad][2048]
  unsigned short* WdtT = (unsigned short*)at(78592);  // 8 MB   [2048][2048]
  unsigned short* WoutT= (unsigned short*)at(86784);  // 4 MB   [1024][2048]
  unsigned short* WwrT = (unsigned short*)at(90880);  // 512 KB [256][1024]  (ends 89.25 MB)

  dim3 blk(256);
  // 0) fused prep: all weight transposes + x cast + WxT pad zero (1 launch)
  prep_k<<<dim3(15520), blk, 0, stream>>>(x, W_in_wrap, W_in, W_x, W_dt, W_out, W_out_wrap,
                                          xb16, WiwT, WinT, WxT, WdtT, WoutT, WwrT);
  // 1) h = x @ W_in_wrap + b_in_wrap  (512 blocks)
  gemm_bf16<64,64,0><<<dim3(1024/64, NTOK/64), blk, 0, stream>>>(xb16, WiwT, NTOK, 1024, 256,
                                                                 256, 256, b_in_wrap, hbuf, nullptr);
  // 2) LayerNorm -> bf16
  ln_k<<<dim3(NTOK), blk, 0, stream>>>(hbuf, ln_g, ln_b, hb);
  // 3) xz = h @ W_in -> xb fp32 | z bf16   (512 blocks, 128x128)
  gemm_bf16<128,128,3><<<dim3(4096/128, NTOK/128), blk, 0, stream>>>(hb, WinT, NTOK, 4096, 1024,
                                                                     1024, 1024, nullptr, xb, zbh);
  // 4) u = silu(conv(xb)) -> bf16
  conv_silu_k<<<dim3(NTOK*D_INNER/256), blk, 0, stream>>>(xb, conv_w, conv_b, ub);
  // 5) proj = u @ W_x -> BC fp32 [.,32] | g bf16 [.,2048]  (528 blocks, 128x64)
  gemm_bf16<128,64,4><<<dim3(2112/64, NTOK/128), blk, 0, stream>>>(ub, WxT, NTOK, PROJ_N, 2048,
                                                                   2048, 2048, nullptr, BC, gb);
  // 6) dt = softplus(g @ W_dt + b_dt) -> fp32 (over xb)   (512 blocks, 128x64)
  gemm_bf16<128,64,1><<<dim3(2048/64, NTOK/128), blk, 0, stream>>>(gb, WdtT, NTOK, 2048, 2048,
                                                                   2048, 2048, b_dt, dtb, nullptr);
  // 7) chunk-parallel scan
  scan_p1<<<dim3(BATCH*NCHUNK*(D_INNER/256)), blk, 0, stream>>>(dtb, ub, BC, A_log, summ);
  scan_p2<<<dim3(BATCH*(D_INNER/256)), blk, 0, stream>>>(summ, h0, outH);
  scan_p3<<<dim3(BATCH*NCHUNK*(D_INNER/256)), blk, 0, stream>>>(dtb, ub, zbh, BC, A_log, D_skip, summ, yb);
  // 8) tmp = y @ W_out -> bf16 (over hb)    (512 blocks, 64x64)
  gemm_bf16<64,64,2><<<dim3(1024/64, NTOK/64), blk, 0, stream>>>(yb, WoutT, NTOK, 1024, 2048,
                                                                 2048, 2048, nullptr, tmpb, nullptr);
  // 9) out = tmp @ W_out_wrap + b_out_wrap (fp32 out, 128 blocks)
  gemm_bf16<64,64,0><<<dim3(256/64, NTOK/64), blk, 0, stream>>>(tmpb, WwrT, NTOK, 256, 1024,
                                                                1024, 1024, b_out_wrap, out, nullptr);
}